// Round 7
// baseline (2906.058 us; speedup 1.0000x reference)
//
#include <hip/hip_runtime.h>

#define CH 64
typedef unsigned int uint;
typedef unsigned short ushort;

typedef __attribute__((ext_vector_type(8))) short bf16x8;
typedef __attribute__((ext_vector_type(4))) float f32x4;

// ---------- bf16 helpers ----------
__device__ __forceinline__ float bf_lo(uint u){ union{uint a;float f;}c; c.a=u<<16; return c.f; }
__device__ __forceinline__ float bf_hi(uint u){ union{uint a;float f;}c; c.a=u&0xffff0000u; return c.f; }
__device__ __forceinline__ ushort f2bf(float f){
    uint a = __float_as_uint(f);
    a = (a + 0x7fffu + ((a>>16)&1u)) >> 16;
    return (ushort)a;
}
__device__ __forceinline__ uint pack2(float lo, float hi){
    return (uint)f2bf(lo) | ((uint)f2bf(hi) << 16);
}
__device__ __forceinline__ void atom_pk(uint* addr, float lo, float hi){
    uint v = pack2(lo, hi);
    asm volatile("global_atomic_pk_add_bf16 %0, %1, off" :: "v"(addr), "v"(v) : "memory");
}

// ---------- merged scatter: 3 independent jobs in one dispatch ----------
// job j: S_j[dst] += bf16(A_j[ia] + B_j[ib]), cnt_j[dst] += 1
// 32 lanes per triangle (2 ch/lane), 2 triangles per wave.
struct ScatJobs {
    const void* A[3]; const void* B[3];
    const int* dst[3]; const int* ia[3]; const int* ib[3];
    uint* S[3]; float* cnt[3];
    int T[3]; int abf[3]; int bbf[3];
};
__global__ __launch_bounds__(256) void scatter3(ScatJobs J)
{
    const int job = blockIdx.x % 3;          // interleave jobs across XCDs
    const int bj  = blockIdx.x / 3;
    const int nbj = gridDim.x / 3;
    const int l32  = threadIdx.x & 31;
    const int half = (threadIdx.x >> 5) & 1;
    const int wave = bj * 4 + (threadIdx.x >> 6);
    const int nwave = nbj * 4;

    const void* A = J.A[job]; const void* B = J.B[job];
    const int* idst = J.dst[job]; const int* iia = J.ia[job]; const int* iib = J.ib[job];
    uint* S = J.S[job]; float* cnt = J.cnt[job];
    const int T = J.T[job];
    const bool abf = J.abf[job] != 0, bbf = J.bbf[job] != 0;

    for (int w = wave; 2 * w < T; w += nwave) {
        const int t = 2 * w + half;
        if (t >= T) continue;
        const int ia = iia[t], ib = iib[t], id = idst[t];
        float ax, ay, bx, by;
        if (abf) { uint u = ((const uint*)A)[(size_t)ia*32 + l32]; ax = bf_lo(u); ay = bf_hi(u); }
        else     { float2 v = ((const float2*)A)[(size_t)ia*32 + l32]; ax = v.x; ay = v.y; }
        if (bbf) { uint u = ((const uint*)B)[(size_t)ib*32 + l32]; bx = bf_lo(u); by = bf_hi(u); }
        else     { float2 v = ((const float2*)B)[(size_t)ib*32 + l32]; bx = v.x; by = v.y; }
        atom_pk(S + (size_t)id*32 + l32, ax+bx, ay+by);
        if (l32 == 0) atomicAdd(&cnt[id], 1.0f);
    }
}

// ---------- fp32 -> packed bf16 row copies ----------
__global__ __launch_bounds__(256) void conv_bf16_kernel(
    const float* __restrict__ src, uint* __restrict__ dst, long n4)
{
    long i = (long)blockIdx.x * blockDim.x + threadIdx.x;
    const long stride = (long)gridDim.x * blockDim.x;
    for (; i < n4; i += stride) {
        const float4 v = ((const float4*)src)[i];
        uint2 o; o.x = pack2(v.x, v.y); o.y = pack2(v.z, v.w);
        ((uint2*)dst)[i] = o;
    }
}

// ---------- prep: fp32 W (k,col) -> bf16 W^T swizzled images (8KB each) ----
struct W10 { const float* p[10]; };
__global__ __launch_bounds__(256) void prep_weights(W10 srcs, char* __restrict__ img)
{
    const float* W = srcs.p[blockIdx.x];
    char* im = img + (size_t)blockIdx.x * 8192;
    for (int idx = threadIdx.x; idx < 4096; idx += 256) {
        const int k = idx >> 6, col = idx & 63;
        *(ushort*)(im + col*128 + ((2*k) ^ ((col&7)<<4))) = f2bf(W[idx]);
    }
}

// ---------- MFMA fused finalize (z^T formulation, 512 thr = 8 waves) ------
// out[r] = mlp( base[r] + SA@WA + cA*bA + SB@WB + cB*bB
//               + (SC[r]+SC[inv])@WC + (cC[r]+cC[inv])*bC )
// 256 rows/block (wave: 2 tiles x 16 rows). LDS: 5x8KB weights + 8x2KB z.
// mfma(A=W^T-frag, B=S-frag) -> D = z^T: lane ln owns row, cols ct*16+grp*4+{0..3}.
template<bool BASEBF>
__global__ __launch_bounds__(512, 4) void fused_finalize_mfma(
    const void* __restrict__ base,
    const uint* __restrict__ SA, const float* __restrict__ cA,
    const uint* __restrict__ SB, const float* __restrict__ cB,
    const uint* __restrict__ SC, const float* __restrict__ cC,
    const int* __restrict__ inv,
    const char* __restrict__ wiA, const char* __restrict__ wiB,
    const char* __restrict__ wiC, const char* __restrict__ wi1,
    const char* __restrict__ wi2,
    const float* __restrict__ bA, const float* __restrict__ bB,
    const float* __restrict__ bC,
    const float* __restrict__ b1, const float* __restrict__ b2,
    int N, float* __restrict__ out, uint* __restrict__ out_bf)
{
    __shared__ __attribute__((aligned(16))) char lds[57344]; // 5*8KB W + 8*2KB z
    const int tid = threadIdx.x;

    // ---- linear, conflict-free copy of 5 pre-swizzled W images ----
    {
        const char* imgs[5] = {wiA, wiB, wiC, wi1, wi2};
        #pragma unroll
        for (int m = 0; m < 5; ++m)
            ((uint4*)(lds + m*8192))[tid] = ((const uint4*)imgs[m])[tid];
    }
    __syncthreads();

    const int w = tid >> 6, lane = tid & 63;
    const int ln = lane & 15, grp = lane >> 4;
    char* zl = lds + 40960 + w * 2048;              // wave-private 16x64 bf16
    const int swz = (ln & 7) << 4;

    auto ldW = [&](int m, int kc, int ct) {
        const int col = ct*16 + ln;
        return *(const bf16x8*)(lds + m*8192 + col*128 + ((kc*64 + grp*16) ^ ((col&7)<<4)));
    };
    auto ldS = [&](const uint* Srow, int kc) {
        union { uint4 u; bf16x8 h; } c;
        c.u = *(const uint4*)(Srow + kc*16 + grp*4);
        return c.h;
    };
    auto ldZl = [&](int kc) {
        return *(const bf16x8*)(zl + ln*128 + ((kc*64 + grp*16) ^ swz));
    };
    auto stZl = [&](int ct, float v0, float v1, float v2, float v3) {
        uint2 u; u.x = pack2(v0, v1); u.y = pack2(v2, v3);
        *(uint2*)(zl + ln*128 + ((ct*32 + grp*8) ^ swz)) = u;
    };

    const f32x4 z4 = {0.f, 0.f, 0.f, 0.f};

    #pragma unroll 1
    for (int t = 0; t < 2; ++t) {
        const int rr = blockIdx.x * 256 + w * 32 + t * 16 + ln;
        const int ra = rr < N ? rr : N - 1;
        const bool valid = rr < N;
        const int iv = inv[ra];
        const float fA = cA[ra], fB = cB[ra], fC = cC[ra] + cC[iv];

        const uint* SArow  = SA + (size_t)ra * 32;
        const uint* SBrow  = SB + (size_t)ra * 32;
        const uint* SCrow  = SC + (size_t)ra * 32;
        const uint* SCrow2 = SC + (size_t)iv * 32;

        f32x4 acc[4] = {z4, z4, z4, z4};
        #pragma unroll
        for (int kc = 0; kc < 2; ++kc) {
            const bf16x8 sA = ldS(SArow, kc);
            const bf16x8 sB = ldS(SBrow, kc);
            const bf16x8 sC = ldS(SCrow, kc);
            const bf16x8 sD = ldS(SCrow2, kc);
            #pragma unroll
            for (int ct = 0; ct < 4; ++ct) {
                const bf16x8 wC = ldW(2, kc, ct);
                acc[ct] = __builtin_amdgcn_mfma_f32_16x16x32_bf16(ldW(0,kc,ct), sA, acc[ct], 0,0,0);
                acc[ct] = __builtin_amdgcn_mfma_f32_16x16x32_bf16(ldW(1,kc,ct), sB, acc[ct], 0,0,0);
                acc[ct] = __builtin_amdgcn_mfma_f32_16x16x32_bf16(wC,          sC, acc[ct], 0,0,0);
                acc[ct] = __builtin_amdgcn_mfma_f32_16x16x32_bf16(wC,          sD, acc[ct], 0,0,0);
            }
        }

        // ---- epilogue: + base + counts*bias; z -> LDS (bf16, b64 writes) ----
        #pragma unroll
        for (int ct = 0; ct < 4; ++ct) {
            const int cb = ct*16 + grp*4;
            const float4 vA = *(const float4*)(bA + cb);
            const float4 vB = *(const float4*)(bB + cb);
            const float4 vC = *(const float4*)(bC + cb);
            float e0, e1, e2, e3;
            if (BASEBF) {
                const uint2 u = *(const uint2*)((const uint*)base + (size_t)ra*32 + (cb>>1));
                e0 = bf_lo(u.x); e1 = bf_hi(u.x); e2 = bf_lo(u.y); e3 = bf_hi(u.y);
            } else {
                const float4 b4 = *(const float4*)((const float*)base + (size_t)ra*64 + cb);
                e0 = b4.x; e1 = b4.y; e2 = b4.z; e3 = b4.w;
            }
            stZl(ct,
                 acc[ct][0] + e0 + fA*vA.x + fB*vB.x + fC*vC.x,
                 acc[ct][1] + e1 + fA*vA.y + fB*vB.y + fC*vC.y,
                 acc[ct][2] + e2 + fA*vA.z + fB*vB.z + fC*vC.z,
                 acc[ct][3] + e3 + fA*vA.w + fB*vB.w + fC*vC.w);
        }
        // zl is wave-private; DS ops within a wave are in-order -> no barrier.

        // ---- MLP layer 1: h = relu(z @ W1 + b1) ----
        f32x4 hacc[4] = {z4, z4, z4, z4};
        #pragma unroll
        for (int kc = 0; kc < 2; ++kc) {
            const bf16x8 zf = ldZl(kc);
            #pragma unroll
            for (int ct = 0; ct < 4; ++ct)
                hacc[ct] = __builtin_amdgcn_mfma_f32_16x16x32_bf16(ldW(3,kc,ct), zf, hacc[ct], 0,0,0);
        }
        #pragma unroll
        for (int ct = 0; ct < 4; ++ct) {
            const int cb = ct*16 + grp*4;
            const float4 v1 = *(const float4*)(b1 + cb);
            stZl(ct, fmaxf(hacc[ct][0] + v1.x, 0.f), fmaxf(hacc[ct][1] + v1.y, 0.f),
                     fmaxf(hacc[ct][2] + v1.z, 0.f), fmaxf(hacc[ct][3] + v1.w, 0.f));
        }

        // ---- MLP layer 2: out = h @ W2 + b2 ----
        f32x4 oacc[4] = {z4, z4, z4, z4};
        #pragma unroll
        for (int kc = 0; kc < 2; ++kc) {
            const bf16x8 hf = ldZl(kc);
            #pragma unroll
            for (int ct = 0; ct < 4; ++ct)
                oacc[ct] = __builtin_amdgcn_mfma_f32_16x16x32_bf16(ldW(4,kc,ct), hf, oacc[ct], 0,0,0);
        }
        #pragma unroll
        for (int ct = 0; ct < 4; ++ct) {
            const int cb = ct*16 + grp*4;
            const float4 v2 = *(const float4*)(b2 + cb);
            const float o0 = oacc[ct][0] + v2.x, o1 = oacc[ct][1] + v2.y;
            const float o2 = oacc[ct][2] + v2.z, o3 = oacc[ct][3] + v2.w;
            if (valid) {
                *(float4*)(out + (size_t)ra*64 + cb) = make_float4(o0, o1, o2, o3);
                if (out_bf) {
                    uint2 u; u.x = pack2(o0, o1); u.y = pack2(o2, o3);
                    *(uint2*)(out_bf + (size_t)ra*32 + (cb>>1)) = u;
                }
            }
        }
    }
}

extern "C" void kernel_launch(void* const* d_in, const int* in_sizes, int n_in,
                              void* d_out, int out_size, void* d_ws, size_t ws_size,
                              hipStream_t stream)
{
    const float* ea  = (const float*)d_in[0];
    const float* ea2 = (const float*)d_in[1];
    const float* Wp  = (const float*)d_in[2];   // (6,64,64)
    const float* bp  = (const float*)d_in[3];   // (6,64)
    const float* W1a = (const float*)d_in[4];
    const float* b1a = (const float*)d_in[5];
    const float* W2a = (const float*)d_in[6];
    const float* b2a = (const float*)d_in[7];
    const float* W1b = (const float*)d_in[8];
    const float* b1b = (const float*)d_in[9];
    const float* W2b = (const float*)d_in[10];
    const float* b2b = (const float*)d_in[11];
    const int* t111 = (const int*)d_in[12];     // [3,T]: ij, ik, kj
    const int* t112 = (const int*)d_in[13];
    const int* t122 = (const int*)d_in[14];
    const int* t222 = (const int*)d_in[15];
    const int* inv1 = (const int*)d_in[16];
    const int* inv2 = (const int*)d_in[17];

    const int E    = in_sizes[0] / CH;
    const int E2   = in_sizes[1] / CH;
    const int T111 = in_sizes[12] / 3;
    const int T112 = in_sizes[13] / 3;
    const int T122 = in_sizes[14] / 3;
    const int T222 = in_sizes[15] / 3;

    float* out1 = (float*)d_out;
    float* out2 = out1 + (size_t)E * CH;

    const size_t R = (size_t)(E > E2 ? E : E2);
    char* p = (char*)d_ws;
    char*  Wimg = p;       p += 10 * 8192;
    uint*  SA = (uint*)p;  p += R * 128;
    uint*  SB = (uint*)p;  p += R * 128;
    uint*  SC = (uint*)p;  p += R * 128;
    float* cA = (float*)p; p += R * 4;
    float* cB = (float*)p; p += R * 4;
    float* cC = (float*)p; p += R * 4;
    size_t used = (size_t)(p - (char*)d_ws);
    uint* ea2_bf = nullptr;
    uint* out1_bf = nullptr;
    uint* ea_bf  = nullptr;
    if (ws_size >= used + (size_t)E2 * 128) { ea2_bf = (uint*)p; p += (size_t)E2 * 128; used += (size_t)E2 * 128; }
    if (ws_size >= used + (size_t)E  * 128) { out1_bf = (uint*)p; p += (size_t)E * 128; used += (size_t)E * 128; }
    if (ws_size >= used + (size_t)E  * 128) { ea_bf  = (uint*)p; }

    const dim3 blk256(256), blk512(512);
    const int SCAT3_NB = 12288;   // multiple of 3; 4096 blocks per job

    // weight images: order {Wp0..Wp5, W1a, W2a, W1b, W2b}
    W10 w10;
    for (int i = 0; i < 6; ++i) w10.p[i] = Wp + (size_t)i * CH * CH;
    w10.p[6] = W1a; w10.p[7] = W2a; w10.p[8] = W1b; w10.p[9] = W2b;
    prep_weights<<<10, blk256, 0, stream>>>(w10, Wimg);

    if (ea2_bf) conv_bf16_kernel<<<2048, blk256, 0, stream>>>(ea2, ea2_bf, (long)E2 * 16);
    if (ea_bf)  conv_bf16_kernel<<<2048, blk256, 0, stream>>>(ea,  ea_bf,  (long)E  * 16);

    const void* eaS  = ea_bf  ? (const void*)ea_bf  : (const void*)ea;
    const void* ea2S = ea2_bf ? (const void*)ea2_bf : (const void*)ea2;
    const int eaB = ea_bf != nullptr, ea2B = ea2_bf != nullptr;

    // ================= Phase 1 (edges1) =================
    hipMemsetAsync(SA, 0, (size_t)E * 128, stream);
    hipMemsetAsync(SB, 0, (size_t)E * 128, stream);
    hipMemsetAsync(SC, 0, (size_t)E * 128, stream);
    hipMemsetAsync(cA, 0, (size_t)E * 4, stream);
    hipMemsetAsync(cB, 0, (size_t)E * 4, stream);
    hipMemsetAsync(cC, 0, (size_t)E * 4, stream);

    {
        ScatJobs J;
        // SA: ea[ik111]+ea[kj111] seg ij111   (-> Wp0)
        J.A[0]=eaS;  J.B[0]=eaS;  J.dst[0]=t111+0;      J.ia[0]=t111+T111; J.ib[0]=t111+2*T111;
        J.S[0]=SA; J.cnt[0]=cA; J.T[0]=T111; J.abf[0]=eaB;  J.bbf[0]=eaB;
        // SB: ea2[ik122]+ea2[kj122] seg ij122 (-> Wp2)
        J.A[1]=ea2S; J.B[1]=ea2S; J.dst[1]=t122+0;      J.ia[1]=t122+T122; J.ib[1]=t122+2*T122;
        J.S[1]=SB; J.cnt[1]=cB; J.T[1]=T122; J.abf[1]=ea2B; J.bbf[1]=ea2B;
        // SC: ea[ik112]+ea2[kj112] seg ij112  (-> Wp1, doubled via inv1)
        J.A[2]=eaS;  J.B[2]=ea2S; J.dst[2]=t112+0;      J.ia[2]=t112+T112; J.ib[2]=t112+2*T112;
        J.S[2]=SC; J.cnt[2]=cC; J.T[2]=T112; J.abf[2]=eaB;  J.bbf[2]=ea2B;
        scatter3<<<SCAT3_NB, blk256, 0, stream>>>(J);
    }

    {
        const int NB = (E + 255) / 256;
        if (eaB)
            fused_finalize_mfma<true><<<NB, blk512, 0, stream>>>(
                (const void*)ea_bf, SA, cA, SB, cB, SC, cC, inv1,
                Wimg + 0*8192, Wimg + 2*8192, Wimg + 1*8192, Wimg + 6*8192, Wimg + 7*8192,
                bp + 0*CH, bp + 2*CH, bp + 1*CH, b1a, b2a, E, out1, out1_bf);
        else
            fused_finalize_mfma<false><<<NB, blk512, 0, stream>>>(
                (const void*)ea, SA, cA, SB, cB, SC, cC, inv1,
                Wimg + 0*8192, Wimg + 2*8192, Wimg + 1*8192, Wimg + 6*8192, Wimg + 7*8192,
                bp + 0*CH, bp + 2*CH, bp + 1*CH, b1a, b2a, E, out1, out1_bf);
    }

    // ================= Phase 2 (edges2) =================
    hipMemsetAsync(SA, 0, (size_t)E2 * 128, stream);
    hipMemsetAsync(SB, 0, (size_t)E2 * 128, stream);
    hipMemsetAsync(SC, 0, (size_t)E2 * 128, stream);
    hipMemsetAsync(cA, 0, (size_t)E2 * 4, stream);
    hipMemsetAsync(cB, 0, (size_t)E2 * 4, stream);
    hipMemsetAsync(cC, 0, (size_t)E2 * 4, stream);

    const void* o1S = out1_bf ? (const void*)out1_bf : (const void*)out1;
    const int o1B = out1_bf != nullptr;

    {
        ScatJobs J;
        // SA: out1[ij112]+out1[ik112] seg kj112 (-> Wp3)
        J.A[0]=o1S;  J.B[0]=o1S;  J.dst[0]=t112+2*T112; J.ia[0]=t112+0;    J.ib[0]=t112+T112;
        J.S[0]=SA; J.cnt[0]=cA; J.T[0]=T112; J.abf[0]=o1B;  J.bbf[0]=o1B;
        // SB: ea2[ik222]+ea2[kj222] seg ij222   (-> Wp5)
        J.A[1]=ea2S; J.B[1]=ea2S; J.dst[1]=t222+0;      J.ia[1]=t222+T222; J.ib[1]=t222+2*T222;
        J.S[1]=SB; J.cnt[1]=cB; J.T[1]=T222; J.abf[1]=ea2B; J.bbf[1]=ea2B;
        // SC: out1[ij122]+ea2[kj122] seg ik122   (-> Wp4, doubled via inv2)
        J.A[2]=o1S;  J.B[2]=ea2S; J.dst[2]=t122+T122;   J.ia[2]=t122+0;    J.ib[2]=t122+2*T122;
        J.S[2]=SC; J.cnt[2]=cC; J.T[2]=T122; J.abf[2]=o1B;  J.bbf[2]=ea2B;
        scatter3<<<SCAT3_NB, blk256, 0, stream>>>(J);
    }

    {
        const int NB = (E2 + 255) / 256;
        if (ea2B)
            fused_finalize_mfma<true><<<NB, blk512, 0, stream>>>(
                (const void*)ea2_bf, SA, cA, SB, cB, SC, cC, inv2,
                Wimg + 3*8192, Wimg + 5*8192, Wimg + 4*8192, Wimg + 8*8192, Wimg + 9*8192,
                bp + 3*CH, bp + 5*CH, bp + 4*CH, b1b, b2b, E2, out2, nullptr);
        else
            fused_finalize_mfma<false><<<NB, blk512, 0, stream>>>(
                (const void*)ea2, SA, cA, SB, cB, SC, cC, inv2,
                Wimg + 3*8192, Wimg + 5*8192, Wimg + 4*8192, Wimg + 8*8192, Wimg + 9*8192,
                bp + 3*CH, bp + 5*CH, bp + 4*CH, b1b, b2b, E2, out2, nullptr);
    }
}

// Round 8
// 1786.175 us; speedup vs baseline: 1.6270x; 1.6270x over previous
//
#include <hip/hip_runtime.h>

#define CH 64
typedef unsigned int uint;
typedef unsigned short ushort;

typedef __attribute__((ext_vector_type(8))) short bf16x8;
typedef __attribute__((ext_vector_type(4))) float f32x4;

// ---------- bf16 helpers ----------
__device__ __forceinline__ float bf_lo(uint u){ union{uint a;float f;}c; c.a=u<<16; return c.f; }
__device__ __forceinline__ float bf_hi(uint u){ union{uint a;float f;}c; c.a=u&0xffff0000u; return c.f; }
__device__ __forceinline__ ushort f2bf(float f){
    uint a = __float_as_uint(f);
    a = (a + 0x7fffu + ((a>>16)&1u)) >> 16;
    return (ushort)a;
}
__device__ __forceinline__ uint pack2(float lo, float hi){
    return (uint)f2bf(lo) | ((uint)f2bf(hi) << 16);
}
__device__ __forceinline__ void atom_pk(uint* addr, float lo, float hi){
    uint v = pack2(lo, hi);
    asm volatile("global_atomic_pk_add_bf16 %0, %1, off" :: "v"(addr), "v"(v) : "memory");
}

// ---------- scatter: S[dst] += bf16(A[ia]+B[ib]), cnt[dst] += 1 ----------
template<bool ABF, bool BBF>
__global__ __launch_bounds__(256) void scatter_sum(
    const void* __restrict__ Av, const void* __restrict__ Bv,
    const int* __restrict__ idx_dst, const int* __restrict__ idx_a,
    const int* __restrict__ idx_b, int T,
    uint* __restrict__ S, float* __restrict__ cnt)
{
    const int l32  = threadIdx.x & 31;
    const int half = (threadIdx.x >> 5) & 1;
    const int wave  = blockIdx.x * (blockDim.x >> 6) + (threadIdx.x >> 6);
    const int nwave = gridDim.x * (blockDim.x >> 6);
    for (int w = wave; 2 * w < T; w += nwave) {
        const int t = 2 * w + half;
        if (t >= T) continue;
        const int ia = idx_a[t], ib = idx_b[t], id = idx_dst[t];
        float ax, ay, bx, by;
        if (ABF) { uint u = ((const uint*)Av)[(size_t)ia*32 + l32]; ax = bf_lo(u); ay = bf_hi(u); }
        else     { float2 v = ((const float2*)Av)[(size_t)ia*32 + l32]; ax = v.x; ay = v.y; }
        if (BBF) { uint u = ((const uint*)Bv)[(size_t)ib*32 + l32]; bx = bf_lo(u); by = bf_hi(u); }
        else     { float2 v = ((const float2*)Bv)[(size_t)ib*32 + l32]; bx = v.x; by = v.y; }
        atom_pk(S + (size_t)id*32 + l32, ax+bx, ay+by);
        if (l32 == 0) atomicAdd(&cnt[id], 1.0f);
    }
}

// ---------- fp32 -> packed bf16 row copies ----------
__global__ __launch_bounds__(256) void conv_bf16_kernel(
    const float* __restrict__ src, uint* __restrict__ dst, long n4)
{
    long i = (long)blockIdx.x * blockDim.x + threadIdx.x;
    const long stride = (long)gridDim.x * blockDim.x;
    for (; i < n4; i += stride) {
        const float4 v = ((const float4*)src)[i];
        uint2 o; o.x = pack2(v.x, v.y); o.y = pack2(v.z, v.w);
        ((uint2*)dst)[i] = o;
    }
}

// ---------- prep: fp32 W (k,col) -> bf16 W^T swizzled images (8KB each) ----
struct W10 { const float* p[10]; };
__global__ __launch_bounds__(256) void prep_weights(W10 srcs, char* __restrict__ img)
{
    const float* W = srcs.p[blockIdx.x];
    char* im = img + (size_t)blockIdx.x * 8192;
    for (int idx = threadIdx.x; idx < 4096; idx += 256) {
        const int k = idx >> 6, col = idx & 63;
        *(ushort*)(im + col*128 + ((2*k) ^ ((col&7)<<4))) = f2bf(W[idx]);
    }
}

// ---------- MFMA fused finalize (R4 structure + prepped images) ----------
// out[r] = mlp( base[r] + SA@WA + cA*bA + SB@WB + cB*bB
//               + (SC[r]+SC[inv])@WC + (cC[r]+cC[inv])*bC )
// Block = 256 thr = 4 waves, 64 rows/block (16 rows/wave, ONE tile per wave).
// mfma(A=S-frag, B=W-frag): D lane: col=l&15, row=4*(l>>4)+reg  [m89-verified]
template<bool BASEBF>
__global__ __launch_bounds__(256) void fused_finalize_mfma(
    const void* __restrict__ base,
    const uint* __restrict__ SA, const float* __restrict__ cA,
    const uint* __restrict__ SB, const float* __restrict__ cB,
    const uint* __restrict__ SC, const float* __restrict__ cC,
    const int* __restrict__ inv,
    const char* __restrict__ wiA, const char* __restrict__ wiB,
    const char* __restrict__ wiC, const char* __restrict__ wi1,
    const char* __restrict__ wi2,
    const float* __restrict__ bA, const float* __restrict__ bB,
    const float* __restrict__ bC,
    const float* __restrict__ b1, const float* __restrict__ b2,
    int N, float* __restrict__ out, uint* __restrict__ out_bf)
{
    __shared__ __attribute__((aligned(16))) char lds[49152]; // 5*8KB W + 4*2KB z
    const int tid = threadIdx.x;

    // ---- linear, conflict-free copy of 5 pre-swizzled W images ----
    {
        const char* imgs[5] = {wiA, wiB, wiC, wi1, wi2};
        #pragma unroll
        for (int m = 0; m < 5; ++m) {
            const uint4* s = (const uint4*)imgs[m];
            uint4* d = (uint4*)(lds + m*8192);
            #pragma unroll
            for (int i = 0; i < 2; ++i) d[tid + 256*i] = s[tid + 256*i];
        }
    }
    __syncthreads();

    const int w = tid >> 6, lane = tid & 63;
    const int ln = lane & 15, grp = lane >> 4;
    const int r0 = blockIdx.x * 64 + w * 16;
    const int ra = (r0 + ln) < N ? (r0 + ln) : (N - 1);   // A-frag row (clamped)
    const int iva = inv[ra];
    char* zl = lds + 40960 + w * 2048;                    // per-wave 16x64 bf16

    auto ldS = [&](const uint* Srow, int kc) {
        union { uint4 u; bf16x8 h; } c;
        c.u = *(const uint4*)(Srow + kc*16 + grp*4);
        return c.h;
    };
    auto ldS2 = [&](const uint* r1, const uint* r2, int kc) {
        const uint4 a = *(const uint4*)(r1 + kc*16 + grp*4);
        const uint4 b = *(const uint4*)(r2 + kc*16 + grp*4);
        union { uint4 u; bf16x8 h; } c;
        c.u.x = pack2(bf_lo(a.x)+bf_lo(b.x), bf_hi(a.x)+bf_hi(b.x));
        c.u.y = pack2(bf_lo(a.y)+bf_lo(b.y), bf_hi(a.y)+bf_hi(b.y));
        c.u.z = pack2(bf_lo(a.z)+bf_lo(b.z), bf_hi(a.z)+bf_hi(b.z));
        c.u.w = pack2(bf_lo(a.w)+bf_lo(b.w), bf_hi(a.w)+bf_hi(b.w));
        return c.h;
    };
    auto ldW = [&](int m, int kc, int ct) {
        const int col = ct*16 + ln;
        const int k2  = (kc*32 + grp*8) * 2;
        return *(const bf16x8*)(lds + m*8192 + col*128 + (k2 ^ ((col&7)<<4)));
    };
    auto ldZ = [&](int kc) {
        const int k2 = (kc*32 + grp*8) * 2;
        return *(const bf16x8*)(zl + ln*128 + (k2 ^ ((ln&7)<<4)));
    };
    auto stZ = [&](int row, int col, float v) {
        *(ushort*)(zl + row*128 + ((2*col) ^ ((row&7)<<4))) = f2bf(v);
    };

    const uint* SArow  = SA + (size_t)ra * 32;
    const uint* SBrow  = SB + (size_t)ra * 32;
    const uint* SCrow  = SC + (size_t)ra * 32;
    const uint* SCrow2 = SC + (size_t)iva * 32;

    const f32x4 z4 = {0.f, 0.f, 0.f, 0.f};
    f32x4 acc[4] = {z4, z4, z4, z4};

    // ---- z = SA@WA + SB@WB + (SC+SCinv)@WC  (K=64 each, 2 chunks of 32) ----
    #pragma unroll
    for (int kc = 0; kc < 2; ++kc) {
        const bf16x8 aA = ldS(SArow, kc);
        const bf16x8 aB = ldS(SBrow, kc);
        const bf16x8 aC = ldS2(SCrow, SCrow2, kc);
        #pragma unroll
        for (int ct = 0; ct < 4; ++ct) {
            acc[ct] = __builtin_amdgcn_mfma_f32_16x16x32_bf16(aA, ldW(0,kc,ct), acc[ct], 0,0,0);
            acc[ct] = __builtin_amdgcn_mfma_f32_16x16x32_bf16(aB, ldW(1,kc,ct), acc[ct], 0,0,0);
            acc[ct] = __builtin_amdgcn_mfma_f32_16x16x32_bf16(aC, ldW(2,kc,ct), acc[ct], 0,0,0);
        }
    }

    // ---- fp32 epilogue: + base + counts*bias; write z to zl as bf16 ----
    #pragma unroll
    for (int reg = 0; reg < 4; ++reg) {
        const int rd = r0 + grp*4 + reg;
        const int rc = rd < N ? rd : (N - 1);
        const float fA = cA[rc], fB = cB[rc];
        const float fC = cC[rc] + cC[inv[rc]];
        #pragma unroll
        for (int ct = 0; ct < 4; ++ct) {
            const int col = ct*16 + ln;
            float e;
            if (BASEBF) {
                const uint u = ((const uint*)base)[(size_t)rc*32 + (col>>1)];
                e = (col & 1) ? bf_hi(u) : bf_lo(u);
            } else {
                e = ((const float*)base)[(size_t)rc*64 + col];
            }
            acc[ct][reg] += e + fA*bA[col] + fB*bB[col] + fC*bC[col];
        }
    }
    #pragma unroll
    for (int ct = 0; ct < 4; ++ct)
        #pragma unroll
        for (int reg = 0; reg < 4; ++reg)
            stZ(grp*4 + reg, ct*16 + ln, acc[ct][reg]);
    // zl is wave-private; DS ops within a wave are in-order -> no barrier.

    // ---- MLP layer 1: h = relu(z @ W1 + b1) ----
    f32x4 hacc[4] = {z4, z4, z4, z4};
    #pragma unroll
    for (int kc = 0; kc < 2; ++kc) {
        const bf16x8 az = ldZ(kc);
        #pragma unroll
        for (int ct = 0; ct < 4; ++ct)
            hacc[ct] = __builtin_amdgcn_mfma_f32_16x16x32_bf16(az, ldW(3,kc,ct), hacc[ct], 0,0,0);
    }
    #pragma unroll
    for (int ct = 0; ct < 4; ++ct)
        #pragma unroll
        for (int reg = 0; reg < 4; ++reg)
            stZ(grp*4 + reg, ct*16 + ln, fmaxf(hacc[ct][reg] + b1[ct*16 + ln], 0.f));

    // ---- MLP layer 2: out = h @ W2 + b2 ----
    f32x4 oacc[4] = {z4, z4, z4, z4};
    #pragma unroll
    for (int kc = 0; kc < 2; ++kc) {
        const bf16x8 ah = ldZ(kc);
        #pragma unroll
        for (int ct = 0; ct < 4; ++ct)
            oacc[ct] = __builtin_amdgcn_mfma_f32_16x16x32_bf16(ah, ldW(4,kc,ct), oacc[ct], 0,0,0);
    }
    #pragma unroll
    for (int reg = 0; reg < 4; ++reg) {
        const int rd = r0 + grp*4 + reg;
        if (rd < N) {
            #pragma unroll
            for (int ct = 0; ct < 4; ++ct) {
                const int col = ct*16 + ln;
                const float o = oacc[ct][reg] + b2[col];
                out[(size_t)rd*64 + col] = o;
                if (out_bf) ((ushort*)out_bf)[(size_t)rd*64 + col] = f2bf(o);
            }
        }
    }
}

extern "C" void kernel_launch(void* const* d_in, const int* in_sizes, int n_in,
                              void* d_out, int out_size, void* d_ws, size_t ws_size,
                              hipStream_t stream)
{
    const float* ea  = (const float*)d_in[0];
    const float* ea2 = (const float*)d_in[1];
    const float* Wp  = (const float*)d_in[2];   // (6,64,64)
    const float* bp  = (const float*)d_in[3];   // (6,64)
    const float* W1a = (const float*)d_in[4];
    const float* b1a = (const float*)d_in[5];
    const float* W2a = (const float*)d_in[6];
    const float* b2a = (const float*)d_in[7];
    const float* W1b = (const float*)d_in[8];
    const float* b1b = (const float*)d_in[9];
    const float* W2b = (const float*)d_in[10];
    const float* b2b = (const float*)d_in[11];
    const int* t111 = (const int*)d_in[12];     // [3,T]: ij, ik, kj
    const int* t112 = (const int*)d_in[13];
    const int* t122 = (const int*)d_in[14];
    const int* t222 = (const int*)d_in[15];
    const int* inv1 = (const int*)d_in[16];
    const int* inv2 = (const int*)d_in[17];

    const int E    = in_sizes[0] / CH;
    const int E2   = in_sizes[1] / CH;
    const int T111 = in_sizes[12] / 3;
    const int T112 = in_sizes[13] / 3;
    const int T122 = in_sizes[14] / 3;
    const int T222 = in_sizes[15] / 3;

    float* out1 = (float*)d_out;
    float* out2 = out1 + (size_t)E * CH;

    const size_t R = (size_t)(E > E2 ? E : E2);
    char* p = (char*)d_ws;
    char*  Wimg = p;       p += 10 * 8192;
    uint*  SA = (uint*)p;  p += R * 128;
    uint*  SB = (uint*)p;  p += R * 128;
    uint*  SC = (uint*)p;  p += R * 128;
    float* cA = (float*)p; p += R * 4;
    float* cB = (float*)p; p += R * 4;
    float* cC = (float*)p; p += R * 4;
    size_t used = (size_t)(p - (char*)d_ws);
    uint* ea2_bf = nullptr;
    uint* out1_bf = nullptr;
    uint* ea_bf  = nullptr;
    if (ws_size >= used + (size_t)E2 * 128) { ea2_bf = (uint*)p; p += (size_t)E2 * 128; used += (size_t)E2 * 128; }
    if (ws_size >= used + (size_t)E  * 128) { out1_bf = (uint*)p; p += (size_t)E * 128; used += (size_t)E * 128; }
    if (ws_size >= used + (size_t)E  * 128) { ea_bf  = (uint*)p; }

    const dim3 blk256(256);
    const int SCAT_NB = 4096;

    auto scat = [&](const void* A, bool abf, const void* B, bool bbf,
                    const int* dst, const int* ia, const int* ib, int T,
                    uint* S, float* c) {
        if (abf && bbf)
            scatter_sum<true, true ><<<SCAT_NB, blk256, 0, stream>>>(A, B, dst, ia, ib, T, S, c);
        else if (abf)
            scatter_sum<true, false><<<SCAT_NB, blk256, 0, stream>>>(A, B, dst, ia, ib, T, S, c);
        else if (bbf)
            scatter_sum<false, true><<<SCAT_NB, blk256, 0, stream>>>(A, B, dst, ia, ib, T, S, c);
        else
            scatter_sum<false, false><<<SCAT_NB, blk256, 0, stream>>>(A, B, dst, ia, ib, T, S, c);
    };

    // weight images: order {Wp0..Wp5, W1a, W2a, W1b, W2b}
    W10 w10;
    for (int i = 0; i < 6; ++i) w10.p[i] = Wp + (size_t)i * CH * CH;
    w10.p[6] = W1a; w10.p[7] = W2a; w10.p[8] = W1b; w10.p[9] = W2b;
    prep_weights<<<10, blk256, 0, stream>>>(w10, Wimg);

    if (ea2_bf) conv_bf16_kernel<<<2048, blk256, 0, stream>>>(ea2, ea2_bf, (long)E2 * 16);
    if (ea_bf)  conv_bf16_kernel<<<2048, blk256, 0, stream>>>(ea,  ea_bf,  (long)E  * 16);

    const void* eaS  = ea_bf  ? (const void*)ea_bf  : (const void*)ea;
    const void* ea2S = ea2_bf ? (const void*)ea2_bf : (const void*)ea2;
    const bool eaB = ea_bf != nullptr, ea2B = ea2_bf != nullptr;

    // ================= Phase 1 (edges1) =================
    hipMemsetAsync(SA, 0, (size_t)E * 128, stream);
    hipMemsetAsync(SB, 0, (size_t)E * 128, stream);
    hipMemsetAsync(SC, 0, (size_t)E * 128, stream);
    hipMemsetAsync(cA, 0, (size_t)E * 4, stream);
    hipMemsetAsync(cB, 0, (size_t)E * 4, stream);
    hipMemsetAsync(cC, 0, (size_t)E * 4, stream);

    // SA: ea[ik111]+ea[kj111] seg ij111   (-> Wp0)
    scat(eaS, eaB, eaS, eaB, t111 + 0, t111 + T111, t111 + 2*T111, T111, SA, cA);
    // SB: ea2[ik122]+ea2[kj122] seg ij122 (-> Wp2)
    scat(ea2S, ea2B, ea2S, ea2B, t122 + 0, t122 + T122, t122 + 2*T122, T122, SB, cB);
    // SC: ea[ik112]+ea2[kj112] seg ij112  (-> Wp1, doubled via inv1)
    scat(eaS, eaB, ea2S, ea2B, t112 + 0, t112 + T112, t112 + 2*T112, T112, SC, cC);

    {
        const int NB = (E + 63) / 64;
        if (eaB)
            fused_finalize_mfma<true><<<NB, blk256, 0, stream>>>(
                (const void*)ea_bf, SA, cA, SB, cB, SC, cC, inv1,
                Wimg + 0*8192, Wimg + 2*8192, Wimg + 1*8192, Wimg + 6*8192, Wimg + 7*8192,
                bp + 0*CH, bp + 2*CH, bp + 1*CH, b1a, b2a, E, out1, out1_bf);
        else
            fused_finalize_mfma<false><<<NB, blk256, 0, stream>>>(
                (const void*)ea, SA, cA, SB, cB, SC, cC, inv1,
                Wimg + 0*8192, Wimg + 2*8192, Wimg + 1*8192, Wimg + 6*8192, Wimg + 7*8192,
                bp + 0*CH, bp + 2*CH, bp + 1*CH, b1a, b2a, E, out1, out1_bf);
    }

    // ================= Phase 2 (edges2) =================
    hipMemsetAsync(SA, 0, (size_t)E2 * 128, stream);
    hipMemsetAsync(SB, 0, (size_t)E2 * 128, stream);
    hipMemsetAsync(SC, 0, (size_t)E2 * 128, stream);
    hipMemsetAsync(cA, 0, (size_t)E2 * 4, stream);
    hipMemsetAsync(cB, 0, (size_t)E2 * 4, stream);
    hipMemsetAsync(cC, 0, (size_t)E2 * 4, stream);

    const void* o1S = out1_bf ? (const void*)out1_bf : (const void*)out1;
    const bool o1B = out1_bf != nullptr;

    // SA: out1[ij112]+out1[ik112] seg kj112 (-> Wp3)
    scat(o1S, o1B, o1S, o1B, t112 + 2*T112, t112 + 0, t112 + T112, T112, SA, cA);
    // SB: ea2[ik222]+ea2[kj222] seg ij222   (-> Wp5)
    scat(ea2S, ea2B, ea2S, ea2B, t222 + 0, t222 + T222, t222 + 2*T222, T222, SB, cB);
    // SC: out1[ij122]+ea2[kj122] seg ik122   (-> Wp4, doubled via inv2)
    scat(o1S, o1B, ea2S, ea2B, t122 + T122, t122 + 0, t122 + 2*T122, T122, SC, cC);

    {
        const int NB = (E2 + 63) / 64;
        if (ea2B)
            fused_finalize_mfma<true><<<NB, blk256, 0, stream>>>(
                (const void*)ea2_bf, SA, cA, SB, cB, SC, cC, inv2,
                Wimg + 3*8192, Wimg + 5*8192, Wimg + 4*8192, Wimg + 8*8192, Wimg + 9*8192,
                bp + 3*CH, bp + 5*CH, bp + 4*CH, b1b, b2b, E2, out2, nullptr);
        else
            fused_finalize_mfma<false><<<NB, blk256, 0, stream>>>(
                (const void*)ea2, SA, cA, SB, cB, SC, cC, inv2,
                Wimg + 3*8192, Wimg + 5*8192, Wimg + 4*8192, Wimg + 8*8192, Wimg + 9*8192,
                bp + 3*CH, bp + 5*CH, bp + 4*CH, b1b, b2b, E2, out2, nullptr);
    }
}

// Round 9
// 1641.747 us; speedup vs baseline: 1.7701x; 1.0880x over previous
//
#include <hip/hip_runtime.h>

#define CH 64
typedef unsigned int uint;
typedef unsigned short ushort;

typedef __attribute__((ext_vector_type(8))) short bf16x8;
typedef __attribute__((ext_vector_type(4))) float f32x4;

// ---------- bf16 helpers ----------
__device__ __forceinline__ float bf_lo(uint u){ union{uint a;float f;}c; c.a=u<<16; return c.f; }
__device__ __forceinline__ float bf_hi(uint u){ union{uint a;float f;}c; c.a=u&0xffff0000u; return c.f; }
__device__ __forceinline__ ushort f2bf(float f){
    uint a = __float_as_uint(f);
    a = (a + 0x7fffu + ((a>>16)&1u)) >> 16;
    return (ushort)a;
}
__device__ __forceinline__ uint pack2(float lo, float hi){
    return (uint)f2bf(lo) | ((uint)f2bf(hi) << 16);
}
// NOTE: volatile keeps the side effect; NO "memory" clobber so the compiler
// may pipeline subsequent loads across the atomic (nothing here reads S).
__device__ __forceinline__ void atom_pk(uint* addr, float lo, float hi){
    uint v = pack2(lo, hi);
    asm volatile("global_atomic_pk_add_bf16 %0, %1, off" :: "v"(addr), "v"(v));
}

// ---------- scatter: S[dst] += bf16(A[ia]+B[ib]), cnt[dst] += 1 ----------
// 32 lanes per triangle (2 ch/lane); 4 triangles per wave per iteration,
// all index+row loads issued before the atomics for cross-triangle ILP.
template<bool ABF, bool BBF>
__global__ __launch_bounds__(256) void scatter_sum(
    const void* __restrict__ Av, const void* __restrict__ Bv,
    const int* __restrict__ idx_dst, const int* __restrict__ idx_a,
    const int* __restrict__ idx_b, int T,
    uint* __restrict__ S, float* __restrict__ cnt)
{
    const int l32  = threadIdx.x & 31;
    const int half = (threadIdx.x >> 5) & 1;
    const int wave  = blockIdx.x * (blockDim.x >> 6) + (threadIdx.x >> 6);
    const int nwave = gridDim.x * (blockDim.x >> 6);

    for (int w = wave; 4 * w < T; w += nwave) {
        const int t0 = 4 * w + half;
        const int t1 = t0 + 2;
        const bool v0 = t0 < T, v1 = t1 < T;
        const int u0 = v0 ? t0 : 0;
        const int u1 = v1 ? t1 : 0;
        const int ia0 = idx_a[u0], ib0 = idx_b[u0], id0 = idx_dst[u0];
        const int ia1 = idx_a[u1], ib1 = idx_b[u1], id1 = idx_dst[u1];

        float ax0, ay0, bx0, by0, ax1, ay1, bx1, by1;
        if (ABF) { uint u = ((const uint*)Av)[(size_t)ia0*32 + l32]; ax0 = bf_lo(u); ay0 = bf_hi(u); }
        else     { float2 v = ((const float2*)Av)[(size_t)ia0*32 + l32]; ax0 = v.x; ay0 = v.y; }
        if (BBF) { uint u = ((const uint*)Bv)[(size_t)ib0*32 + l32]; bx0 = bf_lo(u); by0 = bf_hi(u); }
        else     { float2 v = ((const float2*)Bv)[(size_t)ib0*32 + l32]; bx0 = v.x; by0 = v.y; }
        if (ABF) { uint u = ((const uint*)Av)[(size_t)ia1*32 + l32]; ax1 = bf_lo(u); ay1 = bf_hi(u); }
        else     { float2 v = ((const float2*)Av)[(size_t)ia1*32 + l32]; ax1 = v.x; ay1 = v.y; }
        if (BBF) { uint u = ((const uint*)Bv)[(size_t)ib1*32 + l32]; bx1 = bf_lo(u); by1 = bf_hi(u); }
        else     { float2 v = ((const float2*)Bv)[(size_t)ib1*32 + l32]; bx1 = v.x; by1 = v.y; }

        if (v0) {
            atom_pk(S + (size_t)id0*32 + l32, ax0+bx0, ay0+by0);
            if (l32 == 0) atomicAdd(&cnt[id0], 1.0f);
        }
        if (v1) {
            atom_pk(S + (size_t)id1*32 + l32, ax1+bx1, ay1+by1);
            if (l32 == 0) atomicAdd(&cnt[id1], 1.0f);
        }
    }
}

// ---------- fp32 -> packed bf16 row copies ----------
__global__ __launch_bounds__(256) void conv_bf16_kernel(
    const float* __restrict__ src, uint* __restrict__ dst, long n4)
{
    long i = (long)blockIdx.x * blockDim.x + threadIdx.x;
    const long stride = (long)gridDim.x * blockDim.x;
    for (; i < n4; i += stride) {
        const float4 v = ((const float4*)src)[i];
        uint2 o; o.x = pack2(v.x, v.y); o.y = pack2(v.z, v.w);
        ((uint2*)dst)[i] = o;
    }
}

// ---------- MFMA fused finalize (exact R4 structure: measured 307us @E2) ----
// out[r] = mlp( base[r] + SA@WA + cA*bA + SB@WB + cB*bB
//               + (SC[r]+SC[inv])@WC + (cC[r]+cC[inv])*bC )
// Block = 256 thr = 4 waves, 64 rows/block (16 rows/wave).
__global__ __launch_bounds__(256) void fused_finalize_mfma(
    const float* __restrict__ base,
    const uint* __restrict__ SA, const float* __restrict__ cA,
    const float* __restrict__ WA, const float* __restrict__ bA,
    const uint* __restrict__ SB, const float* __restrict__ cB,
    const float* __restrict__ WB, const float* __restrict__ bB,
    const uint* __restrict__ SC, const float* __restrict__ cC,
    const float* __restrict__ WC, const float* __restrict__ bC,
    const int* __restrict__ inv,
    const float* __restrict__ W1, const float* __restrict__ b1,
    const float* __restrict__ W2, const float* __restrict__ b2,
    int N, float* __restrict__ out, uint* __restrict__ out_bf)
{
    __shared__ __attribute__((aligned(16))) char lds[49152]; // 5*8KB W + 4*2KB z
    const int tid = threadIdx.x;

    // ---- stage 5 weight matrices (fp32 [k][col] -> bf16 W^T, swizzled) ----
    const float* Wlist[5] = {WA, WB, WC, W1, W2};
    #pragma unroll
    for (int m = 0; m < 5; ++m) {
        const float* Wm = Wlist[m];
        for (int idx = tid; idx < 4096; idx += 256) {
            const int k = idx >> 6, col = idx & 63;       // coalesced global read
            *(ushort*)(lds + m*8192 + col*128 + ((2*k) ^ ((col&7)<<4))) = f2bf(Wm[idx]);
        }
    }
    __syncthreads();

    const int w = tid >> 6, lane = tid & 63;
    const int ln = lane & 15, grp = lane >> 4;
    const int r0 = blockIdx.x * 64 + w * 16;
    const int ra = (r0 + ln) < N ? (r0 + ln) : (N - 1);   // A-frag row (clamped)
    const int iva = inv[ra];
    char* zl = lds + 40960 + w * 2048;                    // per-wave 16x64 bf16

    auto ldS = [&](const uint* Srow, int kc) {
        union { uint4 u; bf16x8 h; } c;
        c.u = *(const uint4*)(Srow + kc*16 + grp*4);
        return c.h;
    };
    auto ldS2 = [&](const uint* r1, const uint* r2, int kc) {
        const uint4 a = *(const uint4*)(r1 + kc*16 + grp*4);
        const uint4 b = *(const uint4*)(r2 + kc*16 + grp*4);
        union { uint4 u; bf16x8 h; } c;
        c.u.x = pack2(bf_lo(a.x)+bf_lo(b.x), bf_hi(a.x)+bf_hi(b.x));
        c.u.y = pack2(bf_lo(a.y)+bf_lo(b.y), bf_hi(a.y)+bf_hi(b.y));
        c.u.z = pack2(bf_lo(a.z)+bf_lo(b.z), bf_hi(a.z)+bf_hi(b.z));
        c.u.w = pack2(bf_lo(a.w)+bf_lo(b.w), bf_hi(a.w)+bf_hi(b.w));
        return c.h;
    };
    auto ldW = [&](int m, int kc, int ct) {
        const int col = ct*16 + ln;
        const int k2  = (kc*32 + grp*8) * 2;
        return *(const bf16x8*)(lds + m*8192 + col*128 + (k2 ^ ((col&7)<<4)));
    };
    auto ldZ = [&](int kc) {
        const int k2 = (kc*32 + grp*8) * 2;
        return *(const bf16x8*)(zl + ln*128 + (k2 ^ ((ln&7)<<4)));
    };
    auto stZ = [&](int row, int col, float v) {
        *(ushort*)(zl + row*128 + ((2*col) ^ ((row&7)<<4))) = f2bf(v);
    };

    const uint* SArow  = SA + (size_t)ra * 32;
    const uint* SBrow  = SB + (size_t)ra * 32;
    const uint* SCrow  = SC + (size_t)ra * 32;
    const uint* SCrow2 = SC + (size_t)iva * 32;

    const f32x4 z4 = {0.f, 0.f, 0.f, 0.f};
    f32x4 acc[4] = {z4, z4, z4, z4};

    // ---- z = SA@WA + SB@WB + (SC+SCinv)@WC  (K=64 each, 2 chunks of 32) ----
    #pragma unroll
    for (int kc = 0; kc < 2; ++kc) {
        const bf16x8 aA = ldS(SArow, kc);
        const bf16x8 aB = ldS(SBrow, kc);
        const bf16x8 aC = ldS2(SCrow, SCrow2, kc);
        #pragma unroll
        for (int ct = 0; ct < 4; ++ct) {
            acc[ct] = __builtin_amdgcn_mfma_f32_16x16x32_bf16(aA, ldW(0,kc,ct), acc[ct], 0,0,0);
            acc[ct] = __builtin_amdgcn_mfma_f32_16x16x32_bf16(aB, ldW(1,kc,ct), acc[ct], 0,0,0);
            acc[ct] = __builtin_amdgcn_mfma_f32_16x16x32_bf16(aC, ldW(2,kc,ct), acc[ct], 0,0,0);
        }
    }

    // ---- fp32 epilogue: + base + counts*bias; write z to zl as bf16 ----
    #pragma unroll
    for (int reg = 0; reg < 4; ++reg) {
        const int rd = r0 + grp*4 + reg;
        const int rc = rd < N ? rd : (N - 1);
        const float fA = cA[rc], fB = cB[rc];
        const float fC = cC[rc] + cC[inv[rc]];
        #pragma unroll
        for (int ct = 0; ct < 4; ++ct) {
            const int col = ct*16 + ln;
            acc[ct][reg] += base[(size_t)rc*64 + col] + fA*bA[col] + fB*bB[col] + fC*bC[col];
        }
    }
    #pragma unroll
    for (int ct = 0; ct < 4; ++ct)
        #pragma unroll
        for (int reg = 0; reg < 4; ++reg)
            stZ(grp*4 + reg, ct*16 + ln, acc[ct][reg]);
    // zl is wave-private; DS ops within a wave are in-order -> no barrier.

    // ---- MLP layer 1: h = relu(z @ W1 + b1) ----
    f32x4 hacc[4] = {z4, z4, z4, z4};
    #pragma unroll
    for (int kc = 0; kc < 2; ++kc) {
        const bf16x8 az = ldZ(kc);
        #pragma unroll
        for (int ct = 0; ct < 4; ++ct)
            hacc[ct] = __builtin_amdgcn_mfma_f32_16x16x32_bf16(az, ldW(3,kc,ct), hacc[ct], 0,0,0);
    }
    #pragma unroll
    for (int ct = 0; ct < 4; ++ct)
        #pragma unroll
        for (int reg = 0; reg < 4; ++reg)
            stZ(grp*4 + reg, ct*16 + ln, fmaxf(hacc[ct][reg] + b1[ct*16 + ln], 0.f));

    // ---- MLP layer 2: out = h @ W2 + b2 ----
    f32x4 oacc[4] = {z4, z4, z4, z4};
    #pragma unroll
    for (int kc = 0; kc < 2; ++kc) {
        const bf16x8 ah = ldZ(kc);
        #pragma unroll
        for (int ct = 0; ct < 4; ++ct)
            oacc[ct] = __builtin_amdgcn_mfma_f32_16x16x32_bf16(ah, ldW(4,kc,ct), oacc[ct], 0,0,0);
    }
    #pragma unroll
    for (int reg = 0; reg < 4; ++reg) {
        const int rd = r0 + grp*4 + reg;
        if (rd < N) {
            #pragma unroll
            for (int ct = 0; ct < 4; ++ct) {
                const int col = ct*16 + ln;
                const float o = oacc[ct][reg] + b2[col];
                out[(size_t)rd*64 + col] = o;
                if (out_bf) ((ushort*)out_bf)[(size_t)rd*64 + col] = f2bf(o);
            }
        }
    }
}

extern "C" void kernel_launch(void* const* d_in, const int* in_sizes, int n_in,
                              void* d_out, int out_size, void* d_ws, size_t ws_size,
                              hipStream_t stream)
{
    const float* ea  = (const float*)d_in[0];
    const float* ea2 = (const float*)d_in[1];
    const float* Wp  = (const float*)d_in[2];   // (6,64,64)
    const float* bp  = (const float*)d_in[3];   // (6,64)
    const float* W1a = (const float*)d_in[4];
    const float* b1a = (const float*)d_in[5];
    const float* W2a = (const float*)d_in[6];
    const float* b2a = (const float*)d_in[7];
    const float* W1b = (const float*)d_in[8];
    const float* b1b = (const float*)d_in[9];
    const float* W2b = (const float*)d_in[10];
    const float* b2b = (const float*)d_in[11];
    const int* t111 = (const int*)d_in[12];     // [3,T]: ij, ik, kj
    const int* t112 = (const int*)d_in[13];
    const int* t122 = (const int*)d_in[14];
    const int* t222 = (const int*)d_in[15];
    const int* inv1 = (const int*)d_in[16];
    const int* inv2 = (const int*)d_in[17];

    const int E    = in_sizes[0] / CH;
    const int E2   = in_sizes[1] / CH;
    const int T111 = in_sizes[12] / 3;
    const int T112 = in_sizes[13] / 3;
    const int T122 = in_sizes[14] / 3;
    const int T222 = in_sizes[15] / 3;

    float* out1 = (float*)d_out;
    float* out2 = out1 + (size_t)E * CH;

    const size_t R = (size_t)(E > E2 ? E : E2);
    char* p = (char*)d_ws;
    uint*  SA = (uint*)p;  p += R * 128;
    uint*  SB = (uint*)p;  p += R * 128;
    uint*  SC = (uint*)p;  p += R * 128;
    float* cA = (float*)p; p += R * 4;
    float* cB = (float*)p; p += R * 4;
    float* cC = (float*)p; p += R * 4;
    size_t used = (size_t)(p - (char*)d_ws);
    uint* ea2_bf = nullptr;
    uint* out1_bf = nullptr;
    uint* ea_bf  = nullptr;
    if (ws_size >= used + (size_t)E2 * 128) { ea2_bf = (uint*)p; p += (size_t)E2 * 128; used += (size_t)E2 * 128; }
    if (ws_size >= used + (size_t)E  * 128) { out1_bf = (uint*)p; p += (size_t)E * 128; used += (size_t)E * 128; }
    if (ws_size >= used + (size_t)E  * 128) { ea_bf  = (uint*)p; }

    const dim3 blk256(256);
    const int SCAT_NB = 4096;

    auto scat = [&](const void* A, bool abf, const void* B, bool bbf,
                    const int* dst, const int* ia, const int* ib, int T,
                    uint* S, float* c) {
        if (abf && bbf)
            scatter_sum<true, true ><<<SCAT_NB, blk256, 0, stream>>>(A, B, dst, ia, ib, T, S, c);
        else if (abf)
            scatter_sum<true, false><<<SCAT_NB, blk256, 0, stream>>>(A, B, dst, ia, ib, T, S, c);
        else if (bbf)
            scatter_sum<false, true><<<SCAT_NB, blk256, 0, stream>>>(A, B, dst, ia, ib, T, S, c);
        else
            scatter_sum<false, false><<<SCAT_NB, blk256, 0, stream>>>(A, B, dst, ia, ib, T, S, c);
    };

    if (ea2_bf) conv_bf16_kernel<<<2048, blk256, 0, stream>>>(ea2, ea2_bf, (long)E2 * 16);
    if (ea_bf)  conv_bf16_kernel<<<2048, blk256, 0, stream>>>(ea,  ea_bf,  (long)E  * 16);

    const void* eaS  = ea_bf  ? (const void*)ea_bf  : (const void*)ea;
    const void* ea2S = ea2_bf ? (const void*)ea2_bf : (const void*)ea2;
    const bool eaB = ea_bf != nullptr, ea2B = ea2_bf != nullptr;

    // ================= Phase 1 (edges1) =================
    hipMemsetAsync(SA, 0, (size_t)E * 128, stream);
    hipMemsetAsync(SB, 0, (size_t)E * 128, stream);
    hipMemsetAsync(SC, 0, (size_t)E * 128, stream);
    hipMemsetAsync(cA, 0, (size_t)E * 4, stream);
    hipMemsetAsync(cB, 0, (size_t)E * 4, stream);
    hipMemsetAsync(cC, 0, (size_t)E * 4, stream);

    // SA: ea[ik111]+ea[kj111] seg ij111   (-> Wp0)
    scat(eaS, eaB, eaS, eaB, t111 + 0, t111 + T111, t111 + 2*T111, T111, SA, cA);
    // SB: ea2[ik122]+ea2[kj122] seg ij122 (-> Wp2)
    scat(ea2S, ea2B, ea2S, ea2B, t122 + 0, t122 + T122, t122 + 2*T122, T122, SB, cB);
    // SC: ea[ik112]+ea2[kj112] seg ij112  (-> Wp1, doubled via inv1)
    scat(eaS, eaB, ea2S, ea2B, t112 + 0, t112 + T112, t112 + 2*T112, T112, SC, cC);

    fused_finalize_mfma<<<(E + 63) / 64, blk256, 0, stream>>>(
        ea,
        SA, cA, Wp + 0*CH*CH, bp + 0*CH,
        SB, cB, Wp + 2*CH*CH, bp + 2*CH,
        SC, cC, Wp + 1*CH*CH, bp + 1*CH,
        inv1, W1a, b1a, W2a, b2a, E, out1, out1_bf);

    // ================= Phase 2 (edges2) =================
    hipMemsetAsync(SA, 0, (size_t)E2 * 128, stream);
    hipMemsetAsync(SB, 0, (size_t)E2 * 128, stream);
    hipMemsetAsync(SC, 0, (size_t)E2 * 128, stream);
    hipMemsetAsync(cA, 0, (size_t)E2 * 4, stream);
    hipMemsetAsync(cB, 0, (size_t)E2 * 4, stream);
    hipMemsetAsync(cC, 0, (size_t)E2 * 4, stream);

    const void* o1S = out1_bf ? (const void*)out1_bf : (const void*)out1;
    const bool o1B = out1_bf != nullptr;

    // SA: out1[ij112]+out1[ik112] seg kj112 (-> Wp3)
    scat(o1S, o1B, o1S, o1B, t112 + 2*T112, t112 + 0, t112 + T112, T112, SA, cA);
    // SB: ea2[ik222]+ea2[kj222] seg ij222   (-> Wp5)
    scat(ea2S, ea2B, ea2S, ea2B, t222 + 0, t222 + T222, t222 + 2*T222, T222, SB, cB);
    // SC: out1[ij122]+ea2[kj122] seg ik122   (-> Wp4, doubled via inv2)
    scat(o1S, o1B, ea2S, ea2B, t122 + T122, t122 + 0, t122 + 2*T122, T122, SC, cC);

    fused_finalize_mfma<<<(E2 + 63) / 64, blk256, 0, stream>>>(
        ea2,
        SA, cA, Wp + 3*CH*CH, bp + 3*CH,
        SB, cB, Wp + 5*CH*CH, bp + 5*CH,
        SC, cC, Wp + 4*CH*CH, bp + 4*CH,
        inv2, W1b, b1b, W2b, b2b, E2, out2, nullptr);
}

// Round 10
// 1603.730 us; speedup vs baseline: 1.8121x; 1.0237x over previous
//
#include <hip/hip_runtime.h>

#define CH 64
typedef unsigned int uint;
typedef unsigned short ushort;

typedef __attribute__((ext_vector_type(8))) short bf16x8;
typedef __attribute__((ext_vector_type(4))) float f32x4;

// ---------- bf16 helpers ----------
__device__ __forceinline__ float bf_lo(uint u){ union{uint a;float f;}c; c.a=u<<16; return c.f; }
__device__ __forceinline__ float bf_hi(uint u){ union{uint a;float f;}c; c.a=u&0xffff0000u; return c.f; }
__device__ __forceinline__ ushort f2bf(float f){
    uint a = __float_as_uint(f);
    a = (a + 0x7fffu + ((a>>16)&1u)) >> 16;
    return (ushort)a;
}
__device__ __forceinline__ uint pack2(float lo, float hi){
    return (uint)f2bf(lo) | ((uint)f2bf(hi) << 16);
}
// volatile keeps the side effect; no "memory" clobber so later gathers pipeline.
__device__ __forceinline__ void atom_pk(uint* addr, float lo, float hi){
    uint v = pack2(lo, hi);
    asm volatile("global_atomic_pk_add_bf16 %0, %1, off" :: "v"(addr), "v"(v));
}

// ---------- merged scatter: 3 jobs, contiguous block ranges, depth-8 ----------
// job j: S_j[dst] += bf16(A_j[ia] + B_j[ib]), cnt_j[dst] += 1
// 32 lanes per triangle (2 ch/lane); each half-wave pipelines 4 triangles:
// all index+row loads issued before the 4 atomics (8 gathers in flight / wave).
struct SJob {
    const void* A; const void* B;
    const int* dst; const int* ia; const int* ib;
    uint* S; float* cnt;
    int T; int abf; int bbf;
};
struct SJobs { SJob j[3]; };

__global__ __launch_bounds__(256) void scatter3_deep(SJobs JJ)
{
    const int nbj = gridDim.x / 3;
    int job = blockIdx.x / nbj; if (job > 2) job = 2;
    const int nb = (job == 2) ? (gridDim.x - 2 * nbj) : nbj;
    const int bj = blockIdx.x - job * nbj;

    const SJob J = JJ.j[job];
    const int l32  = threadIdx.x & 31;
    const int half = (threadIdx.x >> 5) & 1;
    const int wave  = bj * 4 + (threadIdx.x >> 6);
    const int nwave = nb * 4;
    const bool abf = J.abf != 0, bbf = J.bbf != 0;
    const int T = J.T;

    for (int t0 = wave * 8 + half * 4; t0 < T; t0 += nwave * 8) {
        int idd[4], iaa[4], ibb[4]; bool v[4];
        #pragma unroll
        for (int k = 0; k < 4; ++k) {
            const int t = t0 + k;
            v[k] = t < T;
            const int u = v[k] ? t : 0;
            iaa[k] = J.ia[u]; ibb[k] = J.ib[u]; idd[k] = J.dst[u];
        }
        float ax[4], ay[4], bx[4], by[4];
        #pragma unroll
        for (int k = 0; k < 4; ++k) {
            if (abf) { uint u = ((const uint*)J.A)[(size_t)iaa[k]*32 + l32]; ax[k]=bf_lo(u); ay[k]=bf_hi(u); }
            else     { float2 f = ((const float2*)J.A)[(size_t)iaa[k]*32 + l32]; ax[k]=f.x; ay[k]=f.y; }
        }
        #pragma unroll
        for (int k = 0; k < 4; ++k) {
            if (bbf) { uint u = ((const uint*)J.B)[(size_t)ibb[k]*32 + l32]; bx[k]=bf_lo(u); by[k]=bf_hi(u); }
            else     { float2 f = ((const float2*)J.B)[(size_t)ibb[k]*32 + l32]; bx[k]=f.x; by[k]=f.y; }
        }
        #pragma unroll
        for (int k = 0; k < 4; ++k) {
            if (v[k]) {
                atom_pk(J.S + (size_t)idd[k]*32 + l32, ax[k]+bx[k], ay[k]+by[k]);
                if (l32 == 0) atomicAdd(&J.cnt[idd[k]], 1.0f);
            }
        }
    }
}

// ---------- fp32 -> packed bf16 row copies ----------
__global__ __launch_bounds__(256) void conv_bf16_kernel(
    const float* __restrict__ src, uint* __restrict__ dst, long n4)
{
    long i = (long)blockIdx.x * blockDim.x + threadIdx.x;
    const long stride = (long)gridDim.x * blockDim.x;
    for (; i < n4; i += stride) {
        const float4 v = ((const float4*)src)[i];
        uint2 o; o.x = pack2(v.x, v.y); o.y = pack2(v.z, v.w);
        ((uint2*)dst)[i] = o;
    }
}

// ---------- MFMA fused finalize (R4 structure: measured local optimum) ----
// out[r] = mlp( base[r] + SA@WA + cA*bA + SB@WB + cB*bB
//               + (SC[r]+SC[inv])@WC + (cC[r]+cC[inv])*bC )
// Block = 256 thr = 4 waves, 64 rows/block (16 rows/wave).
__global__ __launch_bounds__(256) void fused_finalize_mfma(
    const float* __restrict__ base,
    const uint* __restrict__ SA, const float* __restrict__ cA,
    const float* __restrict__ WA, const float* __restrict__ bA,
    const uint* __restrict__ SB, const float* __restrict__ cB,
    const float* __restrict__ WB, const float* __restrict__ bB,
    const uint* __restrict__ SC, const float* __restrict__ cC,
    const float* __restrict__ WC, const float* __restrict__ bC,
    const int* __restrict__ inv,
    const float* __restrict__ W1, const float* __restrict__ b1,
    const float* __restrict__ W2, const float* __restrict__ b2,
    int N, float* __restrict__ out, uint* __restrict__ out_bf)
{
    __shared__ __attribute__((aligned(16))) char lds[49152]; // 5*8KB W + 4*2KB z
    const int tid = threadIdx.x;

    // ---- stage 5 weight matrices (fp32 [k][col] -> bf16 W^T, swizzled) ----
    const float* Wlist[5] = {WA, WB, WC, W1, W2};
    #pragma unroll
    for (int m = 0; m < 5; ++m) {
        const float* Wm = Wlist[m];
        for (int idx = tid; idx < 4096; idx += 256) {
            const int k = idx >> 6, col = idx & 63;       // coalesced global read
            *(ushort*)(lds + m*8192 + col*128 + ((2*k) ^ ((col&7)<<4))) = f2bf(Wm[idx]);
        }
    }
    __syncthreads();

    const int w = tid >> 6, lane = tid & 63;
    const int ln = lane & 15, grp = lane >> 4;
    const int r0 = blockIdx.x * 64 + w * 16;
    const int ra = (r0 + ln) < N ? (r0 + ln) : (N - 1);   // A-frag row (clamped)
    const int iva = inv[ra];
    char* zl = lds + 40960 + w * 2048;                    // per-wave 16x64 bf16

    auto ldS = [&](const uint* Srow, int kc) {
        union { uint4 u; bf16x8 h; } c;
        c.u = *(const uint4*)(Srow + kc*16 + grp*4);
        return c.h;
    };
    auto ldS2 = [&](const uint* r1, const uint* r2, int kc) {
        const uint4 a = *(const uint4*)(r1 + kc*16 + grp*4);
        const uint4 b = *(const uint4*)(r2 + kc*16 + grp*4);
        union { uint4 u; bf16x8 h; } c;
        c.u.x = pack2(bf_lo(a.x)+bf_lo(b.x), bf_hi(a.x)+bf_hi(b.x));
        c.u.y = pack2(bf_lo(a.y)+bf_lo(b.y), bf_hi(a.y)+bf_hi(b.y));
        c.u.z = pack2(bf_lo(a.z)+bf_lo(b.z), bf_hi(a.z)+bf_hi(b.z));
        c.u.w = pack2(bf_lo(a.w)+bf_lo(b.w), bf_hi(a.w)+bf_hi(b.w));
        return c.h;
    };
    auto ldW = [&](int m, int kc, int ct) {
        const int col = ct*16 + ln;
        const int k2  = (kc*32 + grp*8) * 2;
        return *(const bf16x8*)(lds + m*8192 + col*128 + (k2 ^ ((col&7)<<4)));
    };
    auto ldZ = [&](int kc) {
        const int k2 = (kc*32 + grp*8) * 2;
        return *(const bf16x8*)(zl + ln*128 + (k2 ^ ((ln&7)<<4)));
    };
    auto stZ = [&](int row, int col, float v) {
        *(ushort*)(zl + row*128 + ((2*col) ^ ((row&7)<<4))) = f2bf(v);
    };

    const uint* SArow  = SA + (size_t)ra * 32;
    const uint* SBrow  = SB + (size_t)ra * 32;
    const uint* SCrow  = SC + (size_t)ra * 32;
    const uint* SCrow2 = SC + (size_t)iva * 32;

    const f32x4 z4 = {0.f, 0.f, 0.f, 0.f};
    f32x4 acc[4] = {z4, z4, z4, z4};

    // ---- z = SA@WA + SB@WB + (SC+SCinv)@WC  (K=64 each, 2 chunks of 32) ----
    #pragma unroll
    for (int kc = 0; kc < 2; ++kc) {
        const bf16x8 aA = ldS(SArow, kc);
        const bf16x8 aB = ldS(SBrow, kc);
        const bf16x8 aC = ldS2(SCrow, SCrow2, kc);
        #pragma unroll
        for (int ct = 0; ct < 4; ++ct) {
            acc[ct] = __builtin_amdgcn_mfma_f32_16x16x32_bf16(aA, ldW(0,kc,ct), acc[ct], 0,0,0);
            acc[ct] = __builtin_amdgcn_mfma_f32_16x16x32_bf16(aB, ldW(1,kc,ct), acc[ct], 0,0,0);
            acc[ct] = __builtin_amdgcn_mfma_f32_16x16x32_bf16(aC, ldW(2,kc,ct), acc[ct], 0,0,0);
        }
    }

    // ---- fp32 epilogue: + base + counts*bias; write z to zl as bf16 ----
    #pragma unroll
    for (int reg = 0; reg < 4; ++reg) {
        const int rd = r0 + grp*4 + reg;
        const int rc = rd < N ? rd : (N - 1);
        const float fA = cA[rc], fB = cB[rc];
        const float fC = cC[rc] + cC[inv[rc]];
        #pragma unroll
        for (int ct = 0; ct < 4; ++ct) {
            const int col = ct*16 + ln;
            acc[ct][reg] += base[(size_t)rc*64 + col] + fA*bA[col] + fB*bB[col] + fC*bC[col];
        }
    }
    #pragma unroll
    for (int ct = 0; ct < 4; ++ct)
        #pragma unroll
        for (int reg = 0; reg < 4; ++reg)
            stZ(grp*4 + reg, ct*16 + ln, acc[ct][reg]);
    // zl is wave-private; DS ops within a wave are in-order -> no barrier.

    // ---- MLP layer 1: h = relu(z @ W1 + b1) ----
    f32x4 hacc[4] = {z4, z4, z4, z4};
    #pragma unroll
    for (int kc = 0; kc < 2; ++kc) {
        const bf16x8 az = ldZ(kc);
        #pragma unroll
        for (int ct = 0; ct < 4; ++ct)
            hacc[ct] = __builtin_amdgcn_mfma_f32_16x16x32_bf16(az, ldW(3,kc,ct), hacc[ct], 0,0,0);
    }
    #pragma unroll
    for (int ct = 0; ct < 4; ++ct)
        #pragma unroll
        for (int reg = 0; reg < 4; ++reg)
            stZ(grp*4 + reg, ct*16 + ln, fmaxf(hacc[ct][reg] + b1[ct*16 + ln], 0.f));

    // ---- MLP layer 2: out = h @ W2 + b2 ----
    f32x4 oacc[4] = {z4, z4, z4, z4};
    #pragma unroll
    for (int kc = 0; kc < 2; ++kc) {
        const bf16x8 ah = ldZ(kc);
        #pragma unroll
        for (int ct = 0; ct < 4; ++ct)
            oacc[ct] = __builtin_amdgcn_mfma_f32_16x16x32_bf16(ah, ldW(4,kc,ct), oacc[ct], 0,0,0);
    }
    #pragma unroll
    for (int reg = 0; reg < 4; ++reg) {
        const int rd = r0 + grp*4 + reg;
        if (rd < N) {
            #pragma unroll
            for (int ct = 0; ct < 4; ++ct) {
                const int col = ct*16 + ln;
                const float o = oacc[ct][reg] + b2[col];
                out[(size_t)rd*64 + col] = o;
                if (out_bf) ((ushort*)out_bf)[(size_t)rd*64 + col] = f2bf(o);
            }
        }
    }
}

extern "C" void kernel_launch(void* const* d_in, const int* in_sizes, int n_in,
                              void* d_out, int out_size, void* d_ws, size_t ws_size,
                              hipStream_t stream)
{
    const float* ea  = (const float*)d_in[0];
    const float* ea2 = (const float*)d_in[1];
    const float* Wp  = (const float*)d_in[2];   // (6,64,64)
    const float* bp  = (const float*)d_in[3];   // (6,64)
    const float* W1a = (const float*)d_in[4];
    const float* b1a = (const float*)d_in[5];
    const float* W2a = (const float*)d_in[6];
    const float* b2a = (const float*)d_in[7];
    const float* W1b = (const float*)d_in[8];
    const float* b1b = (const float*)d_in[9];
    const float* W2b = (const float*)d_in[10];
    const float* b2b = (const float*)d_in[11];
    const int* t111 = (const int*)d_in[12];     // [3,T]: ij, ik, kj
    const int* t112 = (const int*)d_in[13];
    const int* t122 = (const int*)d_in[14];
    const int* t222 = (const int*)d_in[15];
    const int* inv1 = (const int*)d_in[16];
    const int* inv2 = (const int*)d_in[17];

    const int E    = in_sizes[0] / CH;
    const int E2   = in_sizes[1] / CH;
    const int T111 = in_sizes[12] / 3;
    const int T112 = in_sizes[13] / 3;
    const int T122 = in_sizes[14] / 3;
    const int T222 = in_sizes[15] / 3;

    float* out1 = (float*)d_out;
    float* out2 = out1 + (size_t)E * CH;

    const size_t R = (size_t)(E > E2 ? E : E2);
    char* p = (char*)d_ws;
    uint*  Sbase = (uint*)p;  p += 3 * R * 128;   // packed per phase: [0,E)+[E,2E)+[2E,3E)
    float* cbase = (float*)p; p += 3 * R * 4;
    size_t used = (size_t)(p - (char*)d_ws);
    uint* ea2_bf = nullptr;
    uint* out1_bf = nullptr;
    uint* ea_bf  = nullptr;
    if (ws_size >= used + (size_t)E2 * 128) { ea2_bf = (uint*)p; p += (size_t)E2 * 128; used += (size_t)E2 * 128; }
    if (ws_size >= used + (size_t)E  * 128) { out1_bf = (uint*)p; p += (size_t)E * 128; used += (size_t)E * 128; }
    if (ws_size >= used + (size_t)E  * 128) { ea_bf  = (uint*)p; }

    const dim3 blk256(256);
    const int SCAT_NB = 4096;

    if (ea2_bf) conv_bf16_kernel<<<2048, blk256, 0, stream>>>(ea2, ea2_bf, (long)E2 * 16);
    if (ea_bf)  conv_bf16_kernel<<<2048, blk256, 0, stream>>>(ea,  ea_bf,  (long)E  * 16);

    const void* eaS  = ea_bf  ? (const void*)ea_bf  : (const void*)ea;
    const void* ea2S = ea2_bf ? (const void*)ea2_bf : (const void*)ea2;
    const int eaB = ea_bf != nullptr, ea2B = ea2_bf != nullptr;

    // ================= Phase 1 (edges1) =================
    uint*  SA1 = Sbase;              uint*  SB1 = Sbase + (size_t)E * 32;  uint*  SC1 = Sbase + (size_t)2*E * 32;
    float* cA1 = cbase;              float* cB1 = cbase + E;               float* cC1 = cbase + (size_t)2*E;
    hipMemsetAsync(Sbase, 0, (size_t)3 * E * 128, stream);
    hipMemsetAsync(cbase, 0, (size_t)3 * E * 4, stream);

    {
        SJobs J;
        // SA1: ea[ik111]+ea[kj111] seg ij111   (-> Wp0)
        J.j[0] = {eaS,  eaS,  t111 + 0, t111 + T111, t111 + 2*T111, SA1, cA1, T111, eaB,  eaB};
        // SB1: ea2[ik122]+ea2[kj122] seg ij122 (-> Wp2)
        J.j[1] = {ea2S, ea2S, t122 + 0, t122 + T122, t122 + 2*T122, SB1, cB1, T122, ea2B, ea2B};
        // SC1: ea[ik112]+ea2[kj112] seg ij112  (-> Wp1, doubled via inv1)
        J.j[2] = {eaS,  ea2S, t112 + 0, t112 + T112, t112 + 2*T112, SC1, cC1, T112, eaB,  ea2B};
        scatter3_deep<<<SCAT_NB, blk256, 0, stream>>>(J);
    }

    fused_finalize_mfma<<<(E + 63) / 64, blk256, 0, stream>>>(
        ea,
        SA1, cA1, Wp + 0*CH*CH, bp + 0*CH,
        SB1, cB1, Wp + 2*CH*CH, bp + 2*CH,
        SC1, cC1, Wp + 1*CH*CH, bp + 1*CH,
        inv1, W1a, b1a, W2a, b2a, E, out1, out1_bf);

    // ================= Phase 2 (edges2) =================
    uint*  SA2 = Sbase;              uint*  SB2 = Sbase + (size_t)E2 * 32; uint*  SC2 = Sbase + (size_t)2*E2 * 32;
    float* cA2 = cbase;              float* cB2 = cbase + E2;              float* cC2 = cbase + (size_t)2*E2;
    hipMemsetAsync(Sbase, 0, (size_t)3 * E2 * 128, stream);
    hipMemsetAsync(cbase, 0, (size_t)3 * E2 * 4, stream);

    const void* o1S = out1_bf ? (const void*)out1_bf : (const void*)out1;
    const int o1B = out1_bf != nullptr;

    {
        SJobs J;
        // SA2: out1[ij112]+out1[ik112] seg kj112 (-> Wp3)
        J.j[0] = {o1S,  o1S,  t112 + 2*T112, t112 + 0, t112 + T112,   SA2, cA2, T112, o1B,  o1B};
        // SB2: ea2[ik222]+ea2[kj222] seg ij222   (-> Wp5)
        J.j[1] = {ea2S, ea2S, t222 + 0,      t222 + T222, t222 + 2*T222, SB2, cB2, T222, ea2B, ea2B};
        // SC2: out1[ij122]+ea2[kj122] seg ik122   (-> Wp4, doubled via inv2)
        J.j[2] = {o1S,  ea2S, t122 + T122,   t122 + 0, t122 + 2*T122, SC2, cC2, T122, o1B,  ea2B};
        scatter3_deep<<<SCAT_NB, blk256, 0, stream>>>(J);
    }

    fused_finalize_mfma<<<(E2 + 63) / 64, blk256, 0, stream>>>(
        ea2,
        SA2, cA2, Wp + 3*CH*CH, bp + 3*CH,
        SB2, cB2, Wp + 5*CH*CH, bp + 5*CH,
        SC2, cC2, Wp + 4*CH*CH, bp + 4*CH,
        inv2, W1b, b1b, W2b, b2b, E2, out2, nullptr);
}